// Round 3
// baseline (1324.977 us; speedup 1.0000x reference)
//
#include <hip/hip_runtime.h>
#include <hip/hip_bf16.h>

#define N_NODES 50000
#define N_EDGES 600000
#define DIM_IN  128
#define DIM_OUT 256
#define EPS_BN  1e-5f

// ---- ws layout (float offsets) ----
// agg     : [0, 6,400,000)                 50000*128 f32
// out_gcn : [6,400,000, 19,200,000)        50000*256 f32
// stats   : base 19,200,000: sums[256], sumsq[256], scale[256], shift[256], flag
#define OFF_AGG   0
#define OFF_OG    6400000
#define OFF_STATS 19200000

// Detect whether edges buffer is int64 (flag=1) or int32 (flag=0).
// int64 little-endian entries with values < 50000 have zero high words.
__global__ void k_detect(const unsigned int* __restrict__ e, int* __restrict__ flag) {
    if (threadIdx.x == 0 && blockIdx.x == 0) {
        int nz = 0;
        for (int i = 0; i < 1024; ++i) nz += (e[2 * i + 1] != 0u);
        *flag = (nz == 0) ? 1 : 0;
    }
}

// 32 threads per edge; each thread handles 4 consecutive floats of the row.
__global__ __launch_bounds__(256) void k_scatter(const void* __restrict__ edges,
                                                 const float* __restrict__ x,
                                                 float* __restrict__ agg,
                                                 const int* __restrict__ flag) {
    long long t = (long long)blockIdx.x * blockDim.x + threadIdx.x;
    int e  = (int)(t >> 5);
    int c4 = (int)(t & 31);
    if (e >= N_EDGES) return;
    int s, d;
    if (*flag) {
        const long long* e64 = (const long long*)edges;
        s = (int)e64[e];
        d = (int)e64[N_EDGES + e];
    } else {
        const int* e32 = (const int*)edges;
        s = e32[e];
        d = e32[N_EDGES + e];
    }
    float4 v = *(const float4*)(x + (size_t)s * DIM_IN + c4 * 4);
    float* o = agg + (size_t)d * DIM_IN + c4 * 4;
    atomicAdd(o + 0, v.x);
    atomicAdd(o + 1, v.y);
    atomicAdd(o + 2, v.z);
    atomicAdd(o + 3, v.w);
}

// Dual GEMM: out_gcn = agg@Wg + bg (f32 to ws), sc = x@Ws + bs (f32 to d_out).
// 16-row tiles, 256 threads = one thread per output column.
__global__ __launch_bounds__(256) void k_gemm(const float* __restrict__ agg,
                                              const float* __restrict__ x,
                                              const float* __restrict__ Wg,
                                              const float* __restrict__ bg,
                                              const float* __restrict__ Ws,
                                              const float* __restrict__ bs,
                                              float* __restrict__ og,
                                              float* __restrict__ sc_out) {
    __shared__ float Ag[16][DIM_IN];
    __shared__ float Ax[16][DIM_IN];
    const int r0 = blockIdx.x * 16;
    const int t  = threadIdx.x;

    #pragma unroll
    for (int j = 0; j < 2; ++j) {
        int idx = j * 256 + t;        // float4 index in [0,512)
        int row = idx >> 5;
        int c4  = idx & 31;
        *(float4*)&Ag[row][c4 * 4] = *(const float4*)&agg[(size_t)(r0 + row) * DIM_IN + c4 * 4];
        *(float4*)&Ax[row][c4 * 4] = *(const float4*)&x[(size_t)(r0 + row) * DIM_IN + c4 * 4];
    }
    __syncthreads();

    const int c = t;
    float accg[16], accs[16];
    const float bgc = bg[c], bsc = bs[c];
    #pragma unroll
    for (int r = 0; r < 16; ++r) { accg[r] = bgc; accs[r] = bsc; }

    for (int k4 = 0; k4 < DIM_IN; k4 += 4) {
        float wg[4], wsv[4];
        #pragma unroll
        for (int j = 0; j < 4; ++j) {
            wg[j]  = Wg[(k4 + j) * DIM_OUT + c];
            wsv[j] = Ws[(k4 + j) * DIM_OUT + c];
        }
        #pragma unroll
        for (int r = 0; r < 16; ++r) {
            float4 ag = *(const float4*)&Ag[r][k4];
            float4 ax = *(const float4*)&Ax[r][k4];
            accg[r] += ag.x * wg[0] + ag.y * wg[1] + ag.z * wg[2] + ag.w * wg[3];
            accs[r] += ax.x * wsv[0] + ax.y * wsv[1] + ax.z * wsv[2] + ax.w * wsv[3];
        }
    }

    #pragma unroll
    for (int r = 0; r < 16; ++r) {
        og[(size_t)(r0 + r) * DIM_OUT + c]     = accg[r];
        sc_out[(size_t)(r0 + r) * DIM_OUT + c] = accs[r];
    }
}

// Per-column sum / sumsq with block partials + one atomic per column.
__global__ __launch_bounds__(256) void k_colstats(const float* __restrict__ og,
                                                  float* __restrict__ sums,
                                                  float* __restrict__ sumsq) {
    const int c = threadIdx.x;
    float s = 0.f, q = 0.f;
    for (int r = blockIdx.x; r < N_NODES; r += gridDim.x) {
        float v = og[(size_t)r * DIM_OUT + c];
        s += v;
        q += v * v;
    }
    atomicAdd(&sums[c], s);
    atomicAdd(&sumsq[c], q);
}

__global__ void k_bnparams(const float* __restrict__ sums, const float* __restrict__ sumsq,
                           const float* __restrict__ gamma, const float* __restrict__ beta,
                           float* __restrict__ scale, float* __restrict__ shift) {
    const int c = threadIdx.x;
    const float inv_n = 1.f / (float)N_NODES;
    float mean = sums[c] * inv_n;
    float var  = fmaxf(sumsq[c] * inv_n - mean * mean, 0.f);
    float sc   = gamma[c] * rsqrtf(var + EPS_BN);
    scale[c] = sc;
    shift[c] = beta[c] - mean * sc;
}

// out += elu(og*scale + shift)   (out already holds sc = x@Ws + bs, f32)
__global__ __launch_bounds__(256) void k_final(const float* __restrict__ og,
                                               const float* __restrict__ scale,
                                               const float* __restrict__ shift,
                                               float* __restrict__ out) {
    size_t i4 = (size_t)blockIdx.x * blockDim.x + threadIdx.x;   // float4 index
    size_t base = i4 * 4;
    int c0 = (int)(base & (DIM_OUT - 1));
    float4 v = *(const float4*)(og + base);
    float4 s = *(const float4*)(out + base);

    float vv[4] = {v.x, v.y, v.z, v.w};
    float sv[4] = {s.x, s.y, s.z, s.w};
    float4 o;
    float* op = &o.x;
    #pragma unroll
    for (int j = 0; j < 4; ++j) {
        float b = vv[j] * scale[c0 + j] + shift[c0 + j];
        float e = (b > 0.f) ? b : expm1f(b);
        op[j] = sv[j] + e;
    }
    *(float4*)(out + base) = o;
}

extern "C" void kernel_launch(void* const* d_in, const int* in_sizes, int n_in,
                              void* d_out, int out_size, void* d_ws, size_t ws_size,
                              hipStream_t stream) {
    const float* x     = (const float*)d_in[0];
    const void*  edges = d_in[1];
    const float* Wg    = (const float*)d_in[2];
    const float* bg    = (const float*)d_in[3];
    const float* gamma = (const float*)d_in[4];
    const float* beta  = (const float*)d_in[5];
    const float* Wsc   = (const float*)d_in[6];
    const float* bsc   = (const float*)d_in[7];

    float* ws    = (float*)d_ws;
    float* agg   = ws + OFF_AGG;
    float* og    = ws + OFF_OG;
    float* sums  = ws + OFF_STATS;
    float* sumsq = sums + 256;
    float* scale = sums + 512;
    float* shift = sums + 768;
    int*   flag  = (int*)(sums + 1024);
    float* out   = (float*)d_out;

    hipMemsetAsync(agg, 0, (size_t)N_NODES * DIM_IN * sizeof(float), stream);
    hipMemsetAsync(sums, 0, 512 * sizeof(float), stream);

    k_detect<<<1, 64, 0, stream>>>((const unsigned int*)edges, flag);
    k_scatter<<<(N_EDGES * 32) / 256, 256, 0, stream>>>(edges, x, agg, flag);
    k_gemm<<<N_NODES / 16, 256, 0, stream>>>(agg, x, Wg, bg, Wsc, bsc, og, out);
    k_colstats<<<256, 256, 0, stream>>>(og, sums, sumsq);
    k_bnparams<<<1, 256, 0, stream>>>(sums, sumsq, gamma, beta, scale, shift);
    k_final<<<(N_NODES * DIM_OUT / 4) / 256, 256, 0, stream>>>(og, scale, shift, out);
}

// Round 7
// 428.591 us; speedup vs baseline: 3.0915x; 3.0915x over previous
//
#include <hip/hip_runtime.h>
#include <hip/hip_bf16.h>

#define N_NODES 50000
#define N_EDGES 600000
#define DIM_IN  128
#define DIM_OUT 256
#define EPS_BN  1e-5f
#define NBLK_SCAN 196   // ceil(50000/256)

// ---- ws layout (float offsets) ----
// agg   : [0, 6.4M) f32
// og    : [6.4M, 19.2M) f32  -- int CSR scratch overlaid at its start (used only before k_gemm)
// stats : base 19.2M: sums[256], sumsq[256], scale[256], shift[256], flag
#define OFF_AGG   0
#define OFF_OG    6400000
#define OFF_STATS 19200000

// int overlay inside og region:
//   deg[50000], offs[50001], cursor[50000], bsum[256], boff[256], srcs[600000]

// Detect whether edges buffer is int64 (flag=1) or int32 (flag=0).
__global__ void k_detect(const unsigned int* __restrict__ e, int* __restrict__ flag) {
    if (threadIdx.x == 0 && blockIdx.x == 0) {
        int nz = 0;
        for (int i = 0; i < 1024; ++i) nz += (e[2 * i + 1] != 0u);
        *flag = (nz == 0) ? 1 : 0;
    }
}

__device__ __forceinline__ int load_edge(const void* edges, int idx, int flag) {
    return flag ? (int)((const long long*)edges)[idx] : ((const int*)edges)[idx];
}

__global__ __launch_bounds__(256) void k_hist(const void* __restrict__ edges,
                                              int* __restrict__ deg,
                                              const int* __restrict__ flag) {
    int e = blockIdx.x * 256 + threadIdx.x;
    if (e >= N_EDGES) return;
    int d = load_edge(edges, N_EDGES + e, *flag);
    atomicAdd(&deg[d], 1);
}

__global__ __launch_bounds__(256) void k_scan_a(const int* __restrict__ deg, int* __restrict__ bsum) {
    __shared__ int sm[256];
    int t = threadIdx.x;
    int i = blockIdx.x * 256 + t;
    sm[t] = (i < N_NODES) ? deg[i] : 0;
    __syncthreads();
    for (int s = 128; s > 0; s >>= 1) {
        if (t < s) sm[t] += sm[t + s];
        __syncthreads();
    }
    if (t == 0) bsum[blockIdx.x] = sm[0];
}

__global__ void k_scan_b(const int* __restrict__ bsum, int* __restrict__ boff) {
    __shared__ int sm[256];
    int t = threadIdx.x;
    int v = (t < NBLK_SCAN) ? bsum[t] : 0;
    sm[t] = v;
    __syncthreads();
    for (int o = 1; o < 256; o <<= 1) {
        int u = (t >= o) ? sm[t - o] : 0;
        __syncthreads();
        sm[t] += u;
        __syncthreads();
    }
    boff[t] = sm[t] - v;   // exclusive
}

__global__ __launch_bounds__(256) void k_scan_c(const int* __restrict__ deg,
                                                const int* __restrict__ boff,
                                                int* __restrict__ offs,
                                                int* __restrict__ cursor) {
    __shared__ int sm[256];
    int t = threadIdx.x;
    int i = blockIdx.x * 256 + t;
    int v = (i < N_NODES) ? deg[i] : 0;
    sm[t] = v;
    __syncthreads();
    for (int o = 1; o < 256; o <<= 1) {
        int u = (t >= o) ? sm[t - o] : 0;
        __syncthreads();
        sm[t] += u;
        __syncthreads();
    }
    if (i < N_NODES) {
        int ex = boff[blockIdx.x] + sm[t] - v;
        offs[i] = ex;
        cursor[i] = ex;
    }
    if (i == 0) offs[N_NODES] = N_EDGES;
}

__global__ __launch_bounds__(256) void k_fill(const void* __restrict__ edges,
                                              int* __restrict__ cursor,
                                              int* __restrict__ srcs,
                                              const int* __restrict__ flag) {
    int e = blockIdx.x * 256 + threadIdx.x;
    if (e >= N_EDGES) return;
    int f = *flag;
    int s = load_edge(edges, e, f);
    int d = load_edge(edges, N_EDGES + e, f);
    int slot = atomicAdd(&cursor[d], 1);
    srcs[slot] = s;
}

// One 64-lane wave per dst row; lane accumulates float2 (covers 128 cols).
__global__ __launch_bounds__(256) void k_gather(const float* __restrict__ x,
                                                const int* __restrict__ offs,
                                                const int* __restrict__ srcs,
                                                float* __restrict__ agg) {
    int gid = blockIdx.x * 256 + threadIdx.x;
    int row = gid >> 6;
    int lane = threadIdx.x & 63;
    if (row >= N_NODES) return;
    int b = offs[row], e = offs[row + 1];
    float2 acc = {0.f, 0.f};
    for (int i = b; i < e; ++i) {
        int s = srcs[i];
        float2 v = *(const float2*)(x + (size_t)s * DIM_IN + lane * 2);
        acc.x += v.x;
        acc.y += v.y;
    }
    *(float2*)(agg + (size_t)row * DIM_IN + lane * 2) = acc;
}

// Dual GEMM: out_gcn = agg@Wg + bg (f32 to ws), sc = x@Ws + bs (f32 to d_out).
__global__ __launch_bounds__(256) void k_gemm(const float* __restrict__ agg,
                                              const float* __restrict__ x,
                                              const float* __restrict__ Wg,
                                              const float* __restrict__ bg,
                                              const float* __restrict__ Ws,
                                              const float* __restrict__ bs,
                                              float* __restrict__ og,
                                              float* __restrict__ sc_out) {
    __shared__ float Ag[16][DIM_IN];
    __shared__ float Ax[16][DIM_IN];
    const int r0 = blockIdx.x * 16;
    const int t  = threadIdx.x;

    #pragma unroll
    for (int j = 0; j < 2; ++j) {
        int idx = j * 256 + t;
        int row = idx >> 5;
        int c4  = idx & 31;
        *(float4*)&Ag[row][c4 * 4] = *(const float4*)&agg[(size_t)(r0 + row) * DIM_IN + c4 * 4];
        *(float4*)&Ax[row][c4 * 4] = *(const float4*)&x[(size_t)(r0 + row) * DIM_IN + c4 * 4];
    }
    __syncthreads();

    const int c = t;
    float accg[16], accs[16];
    const float bgc = bg[c], bsc = bs[c];
    #pragma unroll
    for (int r = 0; r < 16; ++r) { accg[r] = bgc; accs[r] = bsc; }

    for (int k4 = 0; k4 < DIM_IN; k4 += 4) {
        float wg[4], wsv[4];
        #pragma unroll
        for (int j = 0; j < 4; ++j) {
            wg[j]  = Wg[(k4 + j) * DIM_OUT + c];
            wsv[j] = Ws[(k4 + j) * DIM_OUT + c];
        }
        #pragma unroll
        for (int r = 0; r < 16; ++r) {
            float4 ag = *(const float4*)&Ag[r][k4];
            float4 ax = *(const float4*)&Ax[r][k4];
            accg[r] += ag.x * wg[0] + ag.y * wg[1] + ag.z * wg[2] + ag.w * wg[3];
            accs[r] += ax.x * wsv[0] + ax.y * wsv[1] + ax.z * wsv[2] + ax.w * wsv[3];
        }
    }

    #pragma unroll
    for (int r = 0; r < 16; ++r) {
        og[(size_t)(r0 + r) * DIM_OUT + c]     = accg[r];
        sc_out[(size_t)(r0 + r) * DIM_OUT + c] = accs[r];
    }
}

__global__ __launch_bounds__(256) void k_colstats(const float* __restrict__ og,
                                                  float* __restrict__ sums,
                                                  float* __restrict__ sumsq) {
    const int c = threadIdx.x;
    float s = 0.f, q = 0.f;
    for (int r = blockIdx.x; r < N_NODES; r += gridDim.x) {
        float v = og[(size_t)r * DIM_OUT + c];
        s += v;
        q += v * v;
    }
    atomicAdd(&sums[c], s);
    atomicAdd(&sumsq[c], q);
}

__global__ void k_bnparams(const float* __restrict__ sums, const float* __restrict__ sumsq,
                           const float* __restrict__ gamma, const float* __restrict__ beta,
                           float* __restrict__ scale, float* __restrict__ shift) {
    const int c = threadIdx.x;
    const float inv_n = 1.f / (float)N_NODES;
    float mean = sums[c] * inv_n;
    float var  = fmaxf(sumsq[c] * inv_n - mean * mean, 0.f);
    float sc   = gamma[c] * rsqrtf(var + EPS_BN);
    scale[c] = sc;
    shift[c] = beta[c] - mean * sc;
}

// out += elu(og*scale + shift)   (out already holds sc = x@Ws + bs, f32)
__global__ __launch_bounds__(256) void k_final(const float* __restrict__ og,
                                               const float* __restrict__ scale,
                                               const float* __restrict__ shift,
                                               float* __restrict__ out) {
    size_t i4 = (size_t)blockIdx.x * blockDim.x + threadIdx.x;
    size_t base = i4 * 4;
    int c0 = (int)(base & (DIM_OUT - 1));
    float4 v = *(const float4*)(og + base);
    float4 s = *(const float4*)(out + base);

    float vv[4] = {v.x, v.y, v.z, v.w};
    float sv[4] = {s.x, s.y, s.z, s.w};
    float4 o;
    float* op = &o.x;
    #pragma unroll
    for (int j = 0; j < 4; ++j) {
        float b = vv[j] * scale[c0 + j] + shift[c0 + j];
        float e = (b > 0.f) ? b : expm1f(b);
        op[j] = sv[j] + e;
    }
    *(float4*)(out + base) = o;
}

extern "C" void kernel_launch(void* const* d_in, const int* in_sizes, int n_in,
                              void* d_out, int out_size, void* d_ws, size_t ws_size,
                              hipStream_t stream) {
    const float* x     = (const float*)d_in[0];
    const void*  edges = d_in[1];
    const float* Wg    = (const float*)d_in[2];
    const float* bg    = (const float*)d_in[3];
    const float* gamma = (const float*)d_in[4];
    const float* beta  = (const float*)d_in[5];
    const float* Wsc   = (const float*)d_in[6];
    const float* bsc   = (const float*)d_in[7];

    float* ws    = (float*)d_ws;
    float* agg   = ws + OFF_AGG;
    float* og    = ws + OFF_OG;
    float* sums  = ws + OFF_STATS;
    float* sumsq = sums + 256;
    float* scale = sums + 512;
    float* shift = sums + 768;
    int*   flag  = (int*)(sums + 1024);
    float* out   = (float*)d_out;

    // CSR scratch overlaid at start of og region (all uses complete before k_gemm writes og)
    int* ib     = (int*)og;
    int* deg    = ib;
    int* offs   = ib + 50000;    // 50001
    int* cursor = ib + 100001;   // 50000
    int* bsum   = ib + 150001;   // 256
    int* boff   = ib + 150257;   // 256
    int* srcs   = ib + 150513;   // 600000

    hipMemsetAsync(deg, 0, N_NODES * sizeof(int), stream);
    hipMemsetAsync(sums, 0, 512 * sizeof(float), stream);

    k_detect<<<1, 64, 0, stream>>>((const unsigned int*)edges, flag);
    k_hist<<<(N_EDGES + 255) / 256, 256, 0, stream>>>(edges, deg, flag);
    k_scan_a<<<NBLK_SCAN, 256, 0, stream>>>(deg, bsum);
    k_scan_b<<<1, 256, 0, stream>>>(bsum, boff);
    k_scan_c<<<NBLK_SCAN, 256, 0, stream>>>(deg, boff, offs, cursor);
    k_fill<<<(N_EDGES + 255) / 256, 256, 0, stream>>>(edges, cursor, srcs, flag);
    k_gather<<<(N_NODES * 64) / 256, 256, 0, stream>>>(x, offs, srcs, agg);
    k_gemm<<<N_NODES / 16, 256, 0, stream>>>(agg, x, Wg, bg, Wsc, bsc, og, out);
    k_colstats<<<256, 256, 0, stream>>>(og, sums, sumsq);
    k_bnparams<<<1, 256, 0, stream>>>(sums, sumsq, gamma, beta, scale, shift);
    k_final<<<(N_NODES * DIM_OUT / 4) / 256, 256, 0, stream>>>(og, scale, shift, out);
}

// Round 8
// 327.113 us; speedup vs baseline: 4.0505x; 1.3102x over previous
//
#include <hip/hip_runtime.h>
#include <hip/hip_bf16.h>

#define N_NODES 50000
#define N_EDGES 600000
#define DIM_IN  128
#define DIM_OUT 256
#define EPS_BN  1e-5f
#define NBLK_SCAN 196   // ceil(50000/256)

// ---- ws layout (float offsets) ----
// agg   : [0, 6.4M) f32
// og    : [6.4M, 19.2M) f32  -- int CSR scratch overlaid at its start (used only before k_gemm)
// stats : base 19.2M: sums[256], sumsq[256], scale[256], shift[256], flag, pad, Wt_g/Wt_s (bf16)
#define OFF_AGG   0
#define OFF_OG    6400000
#define OFF_STATS 19200000

typedef __attribute__((ext_vector_type(8))) short short8;
typedef __attribute__((ext_vector_type(4))) float float4v;

__device__ __forceinline__ unsigned short f2bf(float f) {
    unsigned int x = __builtin_bit_cast(unsigned int, f);
    unsigned int r = (x + 0x7fffu + ((x >> 16) & 1u)) >> 16;   // RNE
    return (unsigned short)r;
}

// Detect whether edges buffer is int64 (flag=1) or int32 (flag=0).
__global__ void k_detect(const unsigned int* __restrict__ e, int* __restrict__ flag) {
    if (threadIdx.x == 0 && blockIdx.x == 0) {
        int nz = 0;
        for (int i = 0; i < 1024; ++i) nz += (e[2 * i + 1] != 0u);
        *flag = (nz == 0) ? 1 : 0;
    }
}

__device__ __forceinline__ int load_edge(const void* edges, int idx, int flag) {
    return flag ? (int)((const long long*)edges)[idx] : ((const int*)edges)[idx];
}

__global__ __launch_bounds__(256) void k_hist(const void* __restrict__ edges,
                                              int* __restrict__ deg,
                                              const int* __restrict__ flag) {
    int e = blockIdx.x * 256 + threadIdx.x;
    if (e >= N_EDGES) return;
    int d = load_edge(edges, N_EDGES + e, *flag);
    atomicAdd(&deg[d], 1);
}

__global__ __launch_bounds__(256) void k_scan_a(const int* __restrict__ deg, int* __restrict__ bsum) {
    __shared__ int sm[256];
    int t = threadIdx.x;
    int i = blockIdx.x * 256 + t;
    sm[t] = (i < N_NODES) ? deg[i] : 0;
    __syncthreads();
    for (int s = 128; s > 0; s >>= 1) {
        if (t < s) sm[t] += sm[t + s];
        __syncthreads();
    }
    if (t == 0) bsum[blockIdx.x] = sm[0];
}

__global__ void k_scan_b(const int* __restrict__ bsum, int* __restrict__ boff) {
    __shared__ int sm[256];
    int t = threadIdx.x;
    int v = (t < NBLK_SCAN) ? bsum[t] : 0;
    sm[t] = v;
    __syncthreads();
    for (int o = 1; o < 256; o <<= 1) {
        int u = (t >= o) ? sm[t - o] : 0;
        __syncthreads();
        sm[t] += u;
        __syncthreads();
    }
    boff[t] = sm[t] - v;   // exclusive
}

__global__ __launch_bounds__(256) void k_scan_c(const int* __restrict__ deg,
                                                const int* __restrict__ boff,
                                                int* __restrict__ offs,
                                                int* __restrict__ cursor) {
    __shared__ int sm[256];
    int t = threadIdx.x;
    int i = blockIdx.x * 256 + t;
    int v = (i < N_NODES) ? deg[i] : 0;
    sm[t] = v;
    __syncthreads();
    for (int o = 1; o < 256; o <<= 1) {
        int u = (t >= o) ? sm[t - o] : 0;
        __syncthreads();
        sm[t] += u;
        __syncthreads();
    }
    if (i < N_NODES) {
        int ex = boff[blockIdx.x] + sm[t] - v;
        offs[i] = ex;
        cursor[i] = ex;
    }
    if (i == 0) offs[N_NODES] = N_EDGES;
}

__global__ __launch_bounds__(256) void k_fill(const void* __restrict__ edges,
                                              int* __restrict__ cursor,
                                              int* __restrict__ srcs,
                                              const int* __restrict__ flag) {
    int e = blockIdx.x * 256 + threadIdx.x;
    if (e >= N_EDGES) return;
    int f = *flag;
    int s = load_edge(edges, e, f);
    int d = load_edge(edges, N_EDGES + e, f);
    int slot = atomicAdd(&cursor[d], 1);
    srcs[slot] = s;
}

// One 64-lane wave per dst row; lane accumulates float2 (covers 128 cols).
__global__ __launch_bounds__(256) void k_gather(const float* __restrict__ x,
                                                const int* __restrict__ offs,
                                                const int* __restrict__ srcs,
                                                float* __restrict__ agg) {
    int gid = blockIdx.x * 256 + threadIdx.x;
    int row = gid >> 6;
    int lane = threadIdx.x & 63;
    if (row >= N_NODES) return;
    int b = offs[row], e = offs[row + 1];
    float2 acc = {0.f, 0.f};
    for (int i = b; i < e; ++i) {
        int s = srcs[i];
        float2 v = *(const float2*)(x + (size_t)s * DIM_IN + lane * 2);
        acc.x += v.x;
        acc.y += v.y;
    }
    *(float2*)(agg + (size_t)row * DIM_IN + lane * 2) = acc;
}

// Convert W [128][256] f32 -> Wt [256][128] bf16 (transposed). block 0: Wg, block 1: Ws.
__global__ __launch_bounds__(256) void k_cvtw(const float* __restrict__ Wg,
                                              const float* __restrict__ Ws,
                                              unsigned short* __restrict__ wtg,
                                              unsigned short* __restrict__ wts) {
    const float* W = blockIdx.x ? Ws : Wg;
    unsigned short* O = blockIdx.x ? wts : wtg;
    int n = threadIdx.x;            // output row = column of W
    for (int k = 0; k < DIM_IN; ++k)
        O[n * DIM_IN + k] = f2bf(W[k * DIM_OUT + n]);
}

// Dual MFMA GEMM: og = agg@Wg + bg (f32), sc = x@Ws + bs (f32 -> d_out).
// Block: 256 thr = 4 waves, tile M=32 x N=256. Wave w: cols [w*64, w*64+64).
// A (agg,x) staged f32->bf16 in LDS, rows padded to 136 shorts (272B).
// B from pre-transposed bf16 Wt[n][k] via 16B global loads (L2-hot).
__global__ __launch_bounds__(256) void k_gemm_mfma(const float* __restrict__ agg,
                                                   const float* __restrict__ x,
                                                   const unsigned short* __restrict__ wtg,
                                                   const unsigned short* __restrict__ wts,
                                                   const float* __restrict__ bg,
                                                   const float* __restrict__ bs,
                                                   float* __restrict__ og,
                                                   float* __restrict__ out) {
    __shared__ short As[32 * 136];
    __shared__ short Xs[32 * 136];
    const int r0 = blockIdx.x * 32;
    const int t = threadIdx.x;
    const int lane = t & 63;
    const int w = t >> 6;

    // ---- stage: thread t -> row t>>3, 16 cols starting at (t&7)*16 ----
    {
        int row = t >> 3;
        int cs  = (t & 7) * 16;
        int grow = r0 + row;
        int base = row * 136 + cs;
        if (grow < N_NODES) {
            const float4* pa = (const float4*)(agg + (size_t)grow * DIM_IN + cs);
            const float4* px = (const float4*)(x   + (size_t)grow * DIM_IN + cs);
            #pragma unroll
            for (int j = 0; j < 2; ++j) {
                float4 a0 = pa[2*j], a1 = pa[2*j+1];
                float4 x0 = px[2*j], x1 = px[2*j+1];
                short8 sa, sx;
                sa[0]=(short)f2bf(a0.x); sa[1]=(short)f2bf(a0.y); sa[2]=(short)f2bf(a0.z); sa[3]=(short)f2bf(a0.w);
                sa[4]=(short)f2bf(a1.x); sa[5]=(short)f2bf(a1.y); sa[6]=(short)f2bf(a1.z); sa[7]=(short)f2bf(a1.w);
                sx[0]=(short)f2bf(x0.x); sx[1]=(short)f2bf(x0.y); sx[2]=(short)f2bf(x0.z); sx[3]=(short)f2bf(x0.w);
                sx[4]=(short)f2bf(x1.x); sx[5]=(short)f2bf(x1.y); sx[6]=(short)f2bf(x1.z); sx[7]=(short)f2bf(x1.w);
                *(short8*)&As[base + j*8] = sa;
                *(short8*)&Xs[base + j*8] = sx;
            }
        } else {
            short8 z = {0,0,0,0,0,0,0,0};
            *(short8*)&As[base] = z; *(short8*)&As[base + 8] = z;
            *(short8*)&Xs[base] = z; *(short8*)&Xs[base + 8] = z;
        }
    }
    __syncthreads();

    const int c0 = w * 64;
    const int lc = lane & 15;       // col-within-tile / row-within-tile
    const int lg = lane >> 4;       // k-group
    const int kg = lg * 8;

    float4v accg[2][4], accs[2][4];
    #pragma unroll
    for (int ct = 0; ct < 4; ++ct) {
        int col = c0 + ct * 16 + lc;
        float bgv = bg[col], bsv = bs[col];
        float4v vg = {bgv, bgv, bgv, bgv};
        float4v vs = {bsv, bsv, bsv, bsv};
        accg[0][ct] = vg; accg[1][ct] = vg;
        accs[0][ct] = vs; accs[1][ct] = vs;
    }

    #pragma unroll
    for (int ks = 0; ks < 4; ++ks) {
        short8 afa[2], afx[2];
        #pragma unroll
        for (int rt = 0; rt < 2; ++rt) {
            int off = (rt * 16 + lc) * 136 + ks * 32 + kg;
            afa[rt] = *(const short8*)&As[off];
            afx[rt] = *(const short8*)&Xs[off];
        }
        #pragma unroll
        for (int ct = 0; ct < 4; ++ct) {
            int col = c0 + ct * 16 + lc;
            size_t woff = (size_t)col * DIM_IN + ks * 32 + kg;
            short8 bfg = *(const short8*)(wtg + woff);
            short8 bfs = *(const short8*)(wts + woff);
            #pragma unroll
            for (int rt = 0; rt < 2; ++rt) {
                accg[rt][ct] = __builtin_amdgcn_mfma_f32_16x16x32_bf16(afa[rt], bfg, accg[rt][ct], 0, 0, 0);
                accs[rt][ct] = __builtin_amdgcn_mfma_f32_16x16x32_bf16(afx[rt], bfs, accs[rt][ct], 0, 0, 0);
            }
        }
    }

    // ---- store: D elem r of lane -> row = rt*16 + lg*4 + r, col = ct*16 + lc ----
    #pragma unroll
    for (int rt = 0; rt < 2; ++rt) {
        #pragma unroll
        for (int r = 0; r < 4; ++r) {
            int row = r0 + rt * 16 + lg * 4 + r;
            if (row < N_NODES) {
                #pragma unroll
                for (int ct = 0; ct < 4; ++ct) {
                    int col = c0 + ct * 16 + lc;
                    og[(size_t)row * DIM_OUT + col]  = accg[rt][ct][r];
                    out[(size_t)row * DIM_OUT + col] = accs[rt][ct][r];
                }
            }
        }
    }
}

__global__ __launch_bounds__(256) void k_colstats(const float* __restrict__ og,
                                                  float* __restrict__ sums,
                                                  float* __restrict__ sumsq) {
    const int c = threadIdx.x;
    float s = 0.f, q = 0.f;
    for (int r = blockIdx.x; r < N_NODES; r += gridDim.x) {
        float v = og[(size_t)r * DIM_OUT + c];
        s += v;
        q += v * v;
    }
    atomicAdd(&sums[c], s);
    atomicAdd(&sumsq[c], q);
}

__global__ void k_bnparams(const float* __restrict__ sums, const float* __restrict__ sumsq,
                           const float* __restrict__ gamma, const float* __restrict__ beta,
                           float* __restrict__ scale, float* __restrict__ shift) {
    const int c = threadIdx.x;
    const float inv_n = 1.f / (float)N_NODES;
    float mean = sums[c] * inv_n;
    float var  = fmaxf(sumsq[c] * inv_n - mean * mean, 0.f);
    float sc   = gamma[c] * rsqrtf(var + EPS_BN);
    scale[c] = sc;
    shift[c] = beta[c] - mean * sc;
}

// out += elu(og*scale + shift)   (out already holds sc = x@Ws + bs, f32)
__global__ __launch_bounds__(256) void k_final(const float* __restrict__ og,
                                               const float* __restrict__ scale,
                                               const float* __restrict__ shift,
                                               float* __restrict__ out) {
    size_t i4 = (size_t)blockIdx.x * blockDim.x + threadIdx.x;
    size_t base = i4 * 4;
    int c0 = (int)(base & (DIM_OUT - 1));
    float4 v = *(const float4*)(og + base);
    float4 s = *(const float4*)(out + base);

    float vv[4] = {v.x, v.y, v.z, v.w};
    float sv[4] = {s.x, s.y, s.z, s.w};
    float4 o;
    float* op = &o.x;
    #pragma unroll
    for (int j = 0; j < 4; ++j) {
        float b = vv[j] * scale[c0 + j] + shift[c0 + j];
        float e = (b > 0.f) ? b : expm1f(b);
        op[j] = sv[j] + e;
    }
    *(float4*)(out + base) = o;
}

extern "C" void kernel_launch(void* const* d_in, const int* in_sizes, int n_in,
                              void* d_out, int out_size, void* d_ws, size_t ws_size,
                              hipStream_t stream) {
    const float* x     = (const float*)d_in[0];
    const void*  edges = d_in[1];
    const float* Wg    = (const float*)d_in[2];
    const float* bg    = (const float*)d_in[3];
    const float* gamma = (const float*)d_in[4];
    const float* beta  = (const float*)d_in[5];
    const float* Wsc   = (const float*)d_in[6];
    const float* bsc   = (const float*)d_in[7];

    float* ws    = (float*)d_ws;
    float* agg   = ws + OFF_AGG;
    float* og    = ws + OFF_OG;
    float* sums  = ws + OFF_STATS;
    float* sumsq = sums + 256;
    float* scale = sums + 512;
    float* shift = sums + 768;
    int*   flag  = (int*)(sums + 1024);
    unsigned short* wtg = (unsigned short*)(sums + 1040);  // 256*128 bf16 = 16384 floats
    unsigned short* wts = wtg + 256 * 128;
    float* out   = (float*)d_out;

    // CSR scratch overlaid at start of og region (all uses complete before k_gemm writes og)
    int* ib     = (int*)og;
    int* deg    = ib;
    int* offs   = ib + 50000;    // 50001
    int* cursor = ib + 100001;   // 50000
    int* bsum   = ib + 150001;   // 256
    int* boff   = ib + 150257;   // 256
    int* srcs   = ib + 150513;   // 600000

    hipMemsetAsync(deg, 0, N_NODES * sizeof(int), stream);
    hipMemsetAsync(sums, 0, 512 * sizeof(float), stream);

    k_detect<<<1, 64, 0, stream>>>((const unsigned int*)edges, flag);
    k_hist<<<(N_EDGES + 255) / 256, 256, 0, stream>>>(edges, deg, flag);
    k_scan_a<<<NBLK_SCAN, 256, 0, stream>>>(deg, bsum);
    k_scan_b<<<1, 256, 0, stream>>>(bsum, boff);
    k_scan_c<<<NBLK_SCAN, 256, 0, stream>>>(deg, boff, offs, cursor);
    k_fill<<<(N_EDGES + 255) / 256, 256, 0, stream>>>(edges, cursor, srcs, flag);
    k_cvtw<<<2, 256, 0, stream>>>(Wg, Wsc, wtg, wts);
    k_gather<<<(N_NODES * 64) / 256, 256, 0, stream>>>(x, offs, srcs, agg);
    k_gemm_mfma<<<(N_NODES + 31) / 32, 256, 0, stream>>>(agg, x, wtg, wts, bg, bsc, og, out);
    k_colstats<<<256, 256, 0, stream>>>(og, sums, sumsq);
    k_bnparams<<<1, 256, 0, stream>>>(sums, sumsq, gamma, beta, scale, shift);
    k_final<<<(N_NODES * DIM_OUT / 4) / 256, 256, 0, stream>>>(og, scale, shift, out);
}

// Round 9
// 281.120 us; speedup vs baseline: 4.7132x; 1.1636x over previous
//
#include <hip/hip_runtime.h>
#include <hip/hip_bf16.h>

#define N_NODES 50000
#define N_EDGES 600000
#define DIM_IN  128
#define DIM_OUT 256
#define EPS_BN  1e-5f
#define NBLK_SCAN 196   // ceil(50000/256)

// ---- ws layout (float offsets) ----
// xb    : [0, 3.2M)        x as bf16 (6.4M ushort)
// aggb  : [3.2M, 6.4M)     agg as bf16 (6.4M ushort)
// ogb   : [6.4M, 12.8M)    og as bf16 (12.8M ushort); CSR int scratch overlaid at start
// stats : base 19.2M: sums[256], sumsq[256], scale[256], shift[256], flag, pad, Wt bf16
#define OFF_XB    0
#define OFF_AGGB  3200000
#define OFF_OG    6400000
#define OFF_STATS 19200000

typedef __attribute__((ext_vector_type(8))) short short8;
typedef __attribute__((ext_vector_type(4))) float float4v;

__device__ __forceinline__ unsigned short f2bf(float f) {
    unsigned int x = __builtin_bit_cast(unsigned int, f);
    unsigned int r = (x + 0x7fffu + ((x >> 16) & 1u)) >> 16;   // RNE
    return (unsigned short)r;
}
__device__ __forceinline__ float bf2f(unsigned short b) {
    unsigned int u = ((unsigned int)b) << 16;
    return __builtin_bit_cast(float, u);
}

// Detect whether edges buffer is int64 (flag=1) or int32 (flag=0). Parallel version,
// same predicate as the (empirically validated) serial one: all first-1024 high words zero.
__global__ void k_detect(const unsigned int* __restrict__ e, int* __restrict__ flag) {
    __shared__ int nz;
    if (threadIdx.x == 0) nz = 0;
    __syncthreads();
    int c = 0;
    for (int i = threadIdx.x; i < 1024; i += 256) c += (e[2 * i + 1] != 0u);
    if (c) atomicAdd(&nz, c);
    __syncthreads();
    if (threadIdx.x == 0) *flag = (nz == 0) ? 1 : 0;
}

__device__ __forceinline__ int load_edge(const void* edges, int idx, int flag) {
    return flag ? (int)((const long long*)edges)[idx] : ((const int*)edges)[idx];
}

__global__ __launch_bounds__(256) void k_hist(const void* __restrict__ edges,
                                              int* __restrict__ deg,
                                              const int* __restrict__ flag) {
    int e = blockIdx.x * 256 + threadIdx.x;
    if (e >= N_EDGES) return;
    int d = load_edge(edges, N_EDGES + e, *flag);
    atomicAdd(&deg[d], 1);
}

__global__ __launch_bounds__(256) void k_scan_a(const int* __restrict__ deg, int* __restrict__ bsum) {
    __shared__ int sm[256];
    int t = threadIdx.x;
    int i = blockIdx.x * 256 + t;
    sm[t] = (i < N_NODES) ? deg[i] : 0;
    __syncthreads();
    for (int s = 128; s > 0; s >>= 1) {
        if (t < s) sm[t] += sm[t + s];
        __syncthreads();
    }
    if (t == 0) bsum[blockIdx.x] = sm[0];
}

__global__ void k_scan_b(const int* __restrict__ bsum, int* __restrict__ boff) {
    __shared__ int sm[256];
    int t = threadIdx.x;
    int v = (t < NBLK_SCAN) ? bsum[t] : 0;
    sm[t] = v;
    __syncthreads();
    for (int o = 1; o < 256; o <<= 1) {
        int u = (t >= o) ? sm[t - o] : 0;
        __syncthreads();
        sm[t] += u;
        __syncthreads();
    }
    boff[t] = sm[t] - v;   // exclusive
}

__global__ __launch_bounds__(256) void k_scan_c(const int* __restrict__ deg,
                                                const int* __restrict__ boff,
                                                int* __restrict__ offs,
                                                int* __restrict__ cursor) {
    __shared__ int sm[256];
    int t = threadIdx.x;
    int i = blockIdx.x * 256 + t;
    int v = (i < N_NODES) ? deg[i] : 0;
    sm[t] = v;
    __syncthreads();
    for (int o = 1; o < 256; o <<= 1) {
        int u = (t >= o) ? sm[t - o] : 0;
        __syncthreads();
        sm[t] += u;
        __syncthreads();
    }
    if (i < N_NODES) {
        int ex = boff[blockIdx.x] + sm[t] - v;
        offs[i] = ex;
        cursor[i] = ex;
    }
    if (i == 0) offs[N_NODES] = N_EDGES;
}

__global__ __launch_bounds__(256) void k_fill(const void* __restrict__ edges,
                                              int* __restrict__ cursor,
                                              int* __restrict__ srcs,
                                              const int* __restrict__ flag) {
    int e = blockIdx.x * 256 + threadIdx.x;
    if (e >= N_EDGES) return;
    int f = *flag;
    int s = load_edge(edges, e, f);
    int d = load_edge(edges, N_EDGES + e, f);
    int slot = atomicAdd(&cursor[d], 1);
    srcs[slot] = s;
}

// x f32 -> xb bf16 (6.4M elements, 8 per thread)
__global__ __launch_bounds__(256) void k_cvtx(const float* __restrict__ x,
                                              unsigned short* __restrict__ xb) {
    size_t i = ((size_t)blockIdx.x * 256 + threadIdx.x) * 8;
    float4 a = *(const float4*)(x + i);
    float4 b = *(const float4*)(x + i + 4);
    short8 s;
    s[0]=(short)f2bf(a.x); s[1]=(short)f2bf(a.y); s[2]=(short)f2bf(a.z); s[3]=(short)f2bf(a.w);
    s[4]=(short)f2bf(b.x); s[5]=(short)f2bf(b.y); s[6]=(short)f2bf(b.z); s[7]=(short)f2bf(b.w);
    *(short8*)(xb + i) = s;
}

// Convert W [128][256] f32 -> Wt [256][128] bf16 (transposed). block 0: Wg, block 1: Ws.
__global__ __launch_bounds__(256) void k_cvtw(const float* __restrict__ Wg,
                                              const float* __restrict__ Ws,
                                              unsigned short* __restrict__ wtg,
                                              unsigned short* __restrict__ wts) {
    const float* W = blockIdx.x ? Ws : Wg;
    unsigned short* O = blockIdx.x ? wts : wtg;
    int n = threadIdx.x;            // output row = column of W
    for (int k = 0; k < DIM_IN; ++k)
        O[n * DIM_IN + k] = f2bf(W[k * DIM_OUT + n]);
}

// One 64-lane wave per dst row; lane covers 2 cols (ushort2 of bf16), f32 accum, bf16 out.
__global__ __launch_bounds__(256) void k_gather(const unsigned short* __restrict__ xb,
                                                const int* __restrict__ offs,
                                                const int* __restrict__ srcs,
                                                unsigned short* __restrict__ aggb) {
    int gid = blockIdx.x * 256 + threadIdx.x;
    int row = gid >> 6;
    int lane = threadIdx.x & 63;
    if (row >= N_NODES) return;
    int b = offs[row], e = offs[row + 1];
    float ax = 0.f, ay = 0.f;
    for (int i = b; i < e; ++i) {
        int s = srcs[i];
        unsigned int u = *(const unsigned int*)(xb + (size_t)s * DIM_IN + lane * 2);
        ax += __builtin_bit_cast(float, u << 16);
        ay += __builtin_bit_cast(float, u & 0xffff0000u);
    }
    unsigned int o = ((unsigned int)f2bf(ax)) | (((unsigned int)f2bf(ay)) << 16);
    *(unsigned int*)(aggb + (size_t)row * DIM_IN + lane * 2) = o;
}

// Dual MFMA GEMM: og(bf16) = agg@Wg + bg, sc(f32->d_out) = x@Ws + bs.
// Block: 256 thr = 4 waves, tile M=32 x N=256. Wave w: cols [w*64, w*64+64).
// A (aggb, xb) copied bf16->LDS, rows padded to 136 shorts (272B -> 2-way bank alias, free).
__global__ __launch_bounds__(256) void k_gemm_mfma(const unsigned short* __restrict__ aggb,
                                                   const unsigned short* __restrict__ xb,
                                                   const unsigned short* __restrict__ wtg,
                                                   const unsigned short* __restrict__ wts,
                                                   const float* __restrict__ bg,
                                                   const float* __restrict__ bs,
                                                   unsigned short* __restrict__ ogb,
                                                   float* __restrict__ out) {
    __shared__ short As[32 * 136];
    __shared__ short Xs[32 * 136];
    const int r0 = blockIdx.x * 32;
    const int t = threadIdx.x;
    const int lane = t & 63;
    const int w = t >> 6;

    // ---- stage: thread t -> row t>>3, 16 shorts at (t&7)*16 ----
    {
        int row = t >> 3;
        int cs  = (t & 7) * 16;
        int grow = r0 + row;
        int base = row * 136 + cs;
        if (grow < N_NODES) {
            const short8* pa = (const short8*)(aggb + (size_t)grow * DIM_IN + cs);
            const short8* px = (const short8*)(xb   + (size_t)grow * DIM_IN + cs);
            *(short8*)&As[base]     = pa[0];
            *(short8*)&As[base + 8] = pa[1];
            *(short8*)&Xs[base]     = px[0];
            *(short8*)&Xs[base + 8] = px[1];
        } else {
            short8 z = {0,0,0,0,0,0,0,0};
            *(short8*)&As[base] = z; *(short8*)&As[base + 8] = z;
            *(short8*)&Xs[base] = z; *(short8*)&Xs[base + 8] = z;
        }
    }
    __syncthreads();

    const int c0 = w * 64;
    const int lc = lane & 15;       // col-within-tile / row-within-tile
    const int lg = lane >> 4;       // k-group
    const int kg = lg * 8;

    float4v accg[2][4], accs[2][4];
    #pragma unroll
    for (int ct = 0; ct < 4; ++ct) {
        int col = c0 + ct * 16 + lc;
        float bgv = bg[col], bsv = bs[col];
        float4v vg = {bgv, bgv, bgv, bgv};
        float4v vs = {bsv, bsv, bsv, bsv};
        accg[0][ct] = vg; accg[1][ct] = vg;
        accs[0][ct] = vs; accs[1][ct] = vs;
    }

    #pragma unroll
    for (int ks = 0; ks < 4; ++ks) {
        short8 afa[2], afx[2];
        #pragma unroll
        for (int rt = 0; rt < 2; ++rt) {
            int off = (rt * 16 + lc) * 136 + ks * 32 + kg;
            afa[rt] = *(const short8*)&As[off];
            afx[rt] = *(const short8*)&Xs[off];
        }
        #pragma unroll
        for (int ct = 0; ct < 4; ++ct) {
            int col = c0 + ct * 16 + lc;
            size_t woff = (size_t)col * DIM_IN + ks * 32 + kg;
            short8 bfg = *(const short8*)(wtg + woff);
            short8 bfs = *(const short8*)(wts + woff);
            #pragma unroll
            for (int rt = 0; rt < 2; ++rt) {
                accg[rt][ct] = __builtin_amdgcn_mfma_f32_16x16x32_bf16(afa[rt], bfg, accg[rt][ct], 0, 0, 0);
                accs[rt][ct] = __builtin_amdgcn_mfma_f32_16x16x32_bf16(afx[rt], bfs, accs[rt][ct], 0, 0, 0);
            }
        }
    }

    // ---- store: D elem r -> row = rt*16 + lg*4 + r, col = ct*16 + lc ----
    #pragma unroll
    for (int rt = 0; rt < 2; ++rt) {
        #pragma unroll
        for (int r = 0; r < 4; ++r) {
            int row = r0 + rt * 16 + lg * 4 + r;
            if (row < N_NODES) {
                #pragma unroll
                for (int ct = 0; ct < 4; ++ct) {
                    int col = c0 + ct * 16 + lc;
                    ogb[(size_t)row * DIM_OUT + col] = f2bf(accg[rt][ct][r]);
                    out[(size_t)row * DIM_OUT + col] = accs[rt][ct][r];
                }
            }
        }
    }
}

__global__ __launch_bounds__(256) void k_colstats(const unsigned short* __restrict__ ogb,
                                                  float* __restrict__ sums,
                                                  float* __restrict__ sumsq) {
    const int c = threadIdx.x;
    float s = 0.f, q = 0.f;
    for (int r = blockIdx.x; r < N_NODES; r += gridDim.x) {
        float v = bf2f(ogb[(size_t)r * DIM_OUT + c]);
        s += v;
        q += v * v;
    }
    atomicAdd(&sums[c], s);
    atomicAdd(&sumsq[c], q);
}

__global__ void k_bnparams(const float* __restrict__ sums, const float* __restrict__ sumsq,
                           const float* __restrict__ gamma, const float* __restrict__ beta,
                           float* __restrict__ scale, float* __restrict__ shift) {
    const int c = threadIdx.x;
    const float inv_n = 1.f / (float)N_NODES;
    float mean = sums[c] * inv_n;
    float var  = fmaxf(sumsq[c] * inv_n - mean * mean, 0.f);
    float sc   = gamma[c] * rsqrtf(var + EPS_BN);
    scale[c] = sc;
    shift[c] = beta[c] - mean * sc;
}

// out += elu(og*scale + shift)   (out already holds sc = x@Ws + bs, f32)
__global__ __launch_bounds__(256) void k_final(const unsigned short* __restrict__ ogb,
                                               const float* __restrict__ scale,
                                               const float* __restrict__ shift,
                                               float* __restrict__ out) {
    size_t i4 = (size_t)blockIdx.x * blockDim.x + threadIdx.x;
    size_t base = i4 * 4;
    int c0 = (int)(base & (DIM_OUT - 1));
    ushort4 v = *(const ushort4*)(ogb + base);
    float4 s = *(const float4*)(out + base);

    float vv[4] = {bf2f(v.x), bf2f(v.y), bf2f(v.z), bf2f(v.w)};
    float sv[4] = {s.x, s.y, s.z, s.w};
    float4 o;
    float* op = &o.x;
    #pragma unroll
    for (int j = 0; j < 4; ++j) {
        float b = vv[j] * scale[c0 + j] + shift[c0 + j];
        float e = (b > 0.f) ? b : expm1f(b);
        op[j] = sv[j] + e;
    }
    *(float4*)(out + base) = o;
}

extern "C" void kernel_launch(void* const* d_in, const int* in_sizes, int n_in,
                              void* d_out, int out_size, void* d_ws, size_t ws_size,
                              hipStream_t stream) {
    const float* x     = (const float*)d_in[0];
    const void*  edges = d_in[1];
    const float* Wg    = (const float*)d_in[2];
    const float* bg    = (const float*)d_in[3];
    const float* gamma = (const float*)d_in[4];
    const float* beta  = (const float*)d_in[5];
    const float* Wsc   = (const float*)d_in[6];
    const float* bsc   = (const float*)d_in[7];

    float* ws    = (float*)d_ws;
    unsigned short* xb   = (unsigned short*)(ws + OFF_XB);
    unsigned short* aggb = (unsigned short*)(ws + OFF_AGGB);
    unsigned short* ogb  = (unsigned short*)(ws + OFF_OG);
    float* sums  = ws + OFF_STATS;
    float* sumsq = sums + 256;
    float* scale = sums + 512;
    float* shift = sums + 768;
    int*   flag  = (int*)(sums + 1024);
    unsigned short* wtg = (unsigned short*)(sums + 1040);  // 256*128 bf16
    unsigned short* wts = wtg + 256 * 128;
    float* out   = (float*)d_out;

    // CSR scratch overlaid at start of og region (dead before k_gemm_mfma writes ogb)
    int* ib     = (int*)(ws + OFF_OG);
    int* deg    = ib;
    int* offs   = ib + 50000;    // 50001
    int* cursor = ib + 100001;   // 50000
    int* bsum   = ib + 150001;   // 256
    int* boff   = ib + 150257;   // 256
    int* srcs   = ib + 150513;   // 600000

    hipMemsetAsync(deg, 0, N_NODES * sizeof(int), stream);
    hipMemsetAsync(sums, 0, 512 * sizeof(float), stream);

    k_detect<<<1, 256, 0, stream>>>((const unsigned int*)edges, flag);
    k_hist<<<(N_EDGES + 255) / 256, 256, 0, stream>>>(edges, deg, flag);
    k_scan_a<<<NBLK_SCAN, 256, 0, stream>>>(deg, bsum);
    k_scan_b<<<1, 256, 0, stream>>>(bsum, boff);
    k_scan_c<<<NBLK_SCAN, 256, 0, stream>>>(deg, boff, offs, cursor);
    k_fill<<<(N_EDGES + 255) / 256, 256, 0, stream>>>(edges, cursor, srcs, flag);
    k_cvtw<<<2, 256, 0, stream>>>(Wg, Wsc, wtg, wts);
    k_cvtx<<<(N_NODES * DIM_IN / 8) / 256, 256, 0, stream>>>(x, xb);
    k_gather<<<(N_NODES * 64) / 256, 256, 0, stream>>>(xb, offs, srcs, aggb);
    k_gemm_mfma<<<(N_NODES + 31) / 32, 256, 0, stream>>>(aggb, xb, wtg, wts, bg, bsc, ogb, out);
    k_colstats<<<256, 256, 0, stream>>>(ogb, sums, sumsq);
    k_bnparams<<<1, 256, 0, stream>>>(sums, sumsq, gamma, beta, scale, shift);
    k_final<<<(N_NODES * DIM_OUT / 4) / 256, 256, 0, stream>>>(ogb, scale, shift, out);
}

// Round 10
// 254.433 us; speedup vs baseline: 5.2076x; 1.1049x over previous
//
#include <hip/hip_runtime.h>
#include <hip/hip_bf16.h>

#define N_NODES 50000
#define N_EDGES 600000
#define DIM_IN  128
#define DIM_OUT 256
#define EPS_BN  1e-5f
#define NBLK_SCAN 196   // ceil(50000/256)
#define NBLK_CVTX 3125  // 50000*128/8/256

// ---- ws layout (float offsets) ----
// xb    : [0, 3.2M)        x as bf16 (6.4M ushort)
// aggb  : [3.2M, 6.4M)     agg as bf16 (6.4M ushort)
// ogb   : [6.4M, 12.8M)    og as bf16 (12.8M ushort); CSR int scratch overlaid at start
// stats : base 19.2M: sums[256], sumsq[256], scale[256], shift[256], flag, pad, Wt bf16
#define OFF_XB    0
#define OFF_AGGB  3200000
#define OFF_OG    6400000
#define OFF_STATS 19200000

typedef __attribute__((ext_vector_type(8))) short short8;
typedef __attribute__((ext_vector_type(4))) float float4v;

__device__ __forceinline__ unsigned short f2bf(float f) {
    unsigned int x = __builtin_bit_cast(unsigned int, f);
    unsigned int r = (x + 0x7fffu + ((x >> 16) & 1u)) >> 16;   // RNE
    return (unsigned short)r;
}
__device__ __forceinline__ float bf2f(unsigned short b) {
    unsigned int u = ((unsigned int)b) << 16;
    return __builtin_bit_cast(float, u);
}

// Detect whether edges buffer is int64 (flag=1) or int32 (flag=0).
__global__ void k_detect(const unsigned int* __restrict__ e, int* __restrict__ flag) {
    __shared__ int nz;
    if (threadIdx.x == 0) nz = 0;
    __syncthreads();
    int c = 0;
    for (int i = threadIdx.x; i < 1024; i += 256) c += (e[2 * i + 1] != 0u);
    if (c) atomicAdd(&nz, c);
    __syncthreads();
    if (threadIdx.x == 0) *flag = (nz == 0) ? 1 : 0;
}

__device__ __forceinline__ int load_edge(const void* edges, int idx, int flag) {
    return flag ? (int)((const long long*)edges)[idx] : ((const int*)edges)[idx];
}

__global__ __launch_bounds__(256) void k_hist(const void* __restrict__ edges,
                                              int* __restrict__ deg,
                                              const int* __restrict__ flag) {
    int e = blockIdx.x * 256 + threadIdx.x;
    if (e >= N_EDGES) return;
    int d = load_edge(edges, N_EDGES + e, *flag);
    atomicAdd(&deg[d], 1);
}

__global__ __launch_bounds__(256) void k_scan_a(const int* __restrict__ deg, int* __restrict__ bsum) {
    __shared__ int sm[256];
    int t = threadIdx.x;
    int i = blockIdx.x * 256 + t;
    sm[t] = (i < N_NODES) ? deg[i] : 0;
    __syncthreads();
    for (int s = 128; s > 0; s >>= 1) {
        if (t < s) sm[t] += sm[t + s];
        __syncthreads();
    }
    if (t == 0) bsum[blockIdx.x] = sm[0];
}

__global__ void k_scan_b(const int* __restrict__ bsum, int* __restrict__ boff) {
    __shared__ int sm[256];
    int t = threadIdx.x;
    int v = (t < NBLK_SCAN) ? bsum[t] : 0;
    sm[t] = v;
    __syncthreads();
    for (int o = 1; o < 256; o <<= 1) {
        int u = (t >= o) ? sm[t - o] : 0;
        __syncthreads();
        sm[t] += u;
        __syncthreads();
    }
    boff[t] = sm[t] - v;   // exclusive
}

__global__ __launch_bounds__(256) void k_scan_c(const int* __restrict__ deg,
                                                const int* __restrict__ boff,
                                                int* __restrict__ offs,
                                                int* __restrict__ cursor) {
    __shared__ int sm[256];
    int t = threadIdx.x;
    int i = blockIdx.x * 256 + t;
    int v = (i < N_NODES) ? deg[i] : 0;
    sm[t] = v;
    __syncthreads();
    for (int o = 1; o < 256; o <<= 1) {
        int u = (t >= o) ? sm[t - o] : 0;
        __syncthreads();
        sm[t] += u;
        __syncthreads();
    }
    if (i < N_NODES) {
        int ex = boff[blockIdx.x] + sm[t] - v;
        offs[i] = ex;
        cursor[i] = ex;
    }
    if (i == 0) offs[N_NODES] = N_EDGES;
}

__global__ __launch_bounds__(256) void k_fill(const void* __restrict__ edges,
                                              int* __restrict__ cursor,
                                              int* __restrict__ srcs,
                                              const int* __restrict__ flag) {
    int e = blockIdx.x * 256 + threadIdx.x;
    if (e >= N_EDGES) return;
    int f = *flag;
    int s = load_edge(edges, e, f);
    int d = load_edge(edges, N_EDGES + e, f);
    int slot = atomicAdd(&cursor[d], 1);
    srcs[slot] = s;
}

// Merged conversions: blocks [0, NBLK_CVTX) convert x -> xb (bf16);
// block NBLK_CVTX transposes+converts both weight matrices.
__global__ __launch_bounds__(256) void k_cvt(const float* __restrict__ x,
                                             const float* __restrict__ Wg,
                                             const float* __restrict__ Ws,
                                             unsigned short* __restrict__ xb,
                                             unsigned short* __restrict__ wtg,
                                             unsigned short* __restrict__ wts) {
    int bid = blockIdx.x;
    if (bid < NBLK_CVTX) {
        size_t i = ((size_t)bid * 256 + threadIdx.x) * 8;
        float4 a = *(const float4*)(x + i);
        float4 b = *(const float4*)(x + i + 4);
        short8 s;
        s[0]=(short)f2bf(a.x); s[1]=(short)f2bf(a.y); s[2]=(short)f2bf(a.z); s[3]=(short)f2bf(a.w);
        s[4]=(short)f2bf(b.x); s[5]=(short)f2bf(b.y); s[6]=(short)f2bf(b.z); s[7]=(short)f2bf(b.w);
        *(short8*)(xb + i) = s;
    } else {
        int n = threadIdx.x;
        for (int k = 0; k < DIM_IN; ++k) {
            wtg[n * DIM_IN + k] = f2bf(Wg[k * DIM_OUT + n]);
            wts[n * DIM_IN + k] = f2bf(Ws[k * DIM_OUT + n]);
        }
    }
}

// One 64-lane wave per dst row; lane covers 2 cols. Src indices are loaded 64-at-a-time
// coalesced, shfl-broadcast; row loads issued in unrolled groups of 4 (independent -> MLP).
__global__ __launch_bounds__(256) void k_gather(const unsigned short* __restrict__ xb,
                                                const int* __restrict__ offs,
                                                const int* __restrict__ srcs,
                                                unsigned short* __restrict__ aggb) {
    int gid = blockIdx.x * 256 + threadIdx.x;
    int row = gid >> 6;
    int lane = threadIdx.x & 63;
    int b = offs[row], e = offs[row + 1];
    float ax = 0.f, ay = 0.f;
    for (int i0 = b; i0 < e; i0 += 64) {
        int cnt = min(64, e - i0);
        int si = (i0 + lane < e) ? srcs[i0 + lane] : 0;
        int j = 0;
        for (; j + 4 <= cnt; j += 4) {
            float tx[4], ty[4];
            #pragma unroll
            for (int u4 = 0; u4 < 4; ++u4) {
                int s = __shfl(si, j + u4, 64);
                unsigned int u = *(const unsigned int*)(xb + (size_t)s * DIM_IN + lane * 2);
                tx[u4] = __builtin_bit_cast(float, u << 16);
                ty[u4] = __builtin_bit_cast(float, u & 0xffff0000u);
            }
            ax += (tx[0] + tx[1]) + (tx[2] + tx[3]);
            ay += (ty[0] + ty[1]) + (ty[2] + ty[3]);
        }
        for (; j < cnt; ++j) {
            int s = __shfl(si, j, 64);
            unsigned int u = *(const unsigned int*)(xb + (size_t)s * DIM_IN + lane * 2);
            ax += __builtin_bit_cast(float, u << 16);
            ay += __builtin_bit_cast(float, u & 0xffff0000u);
        }
    }
    unsigned int o = ((unsigned int)f2bf(ax)) | (((unsigned int)f2bf(ay)) << 16);
    *(unsigned int*)(aggb + (size_t)row * DIM_IN + lane * 2) = o;
}

// Dual MFMA GEMM: og(bf16) = agg@Wg + bg, sc(f32->d_out) = x@Ws + bs.
__global__ __launch_bounds__(256) void k_gemm_mfma(const unsigned short* __restrict__ aggb,
                                                   const unsigned short* __restrict__ xb,
                                                   const unsigned short* __restrict__ wtg,
                                                   const unsigned short* __restrict__ wts,
                                                   const float* __restrict__ bg,
                                                   const float* __restrict__ bs,
                                                   unsigned short* __restrict__ ogb,
                                                   float* __restrict__ out) {
    __shared__ short As[32 * 136];
    __shared__ short Xs[32 * 136];
    const int r0 = blockIdx.x * 32;
    const int t = threadIdx.x;
    const int lane = t & 63;
    const int w = t >> 6;

    {
        int row = t >> 3;
        int cs  = (t & 7) * 16;
        int grow = r0 + row;
        int base = row * 136 + cs;
        if (grow < N_NODES) {
            const short8* pa = (const short8*)(aggb + (size_t)grow * DIM_IN + cs);
            const short8* px = (const short8*)(xb   + (size_t)grow * DIM_IN + cs);
            *(short8*)&As[base]     = pa[0];
            *(short8*)&As[base + 8] = pa[1];
            *(short8*)&Xs[base]     = px[0];
            *(short8*)&Xs[base + 8] = px[1];
        } else {
            short8 z = {0,0,0,0,0,0,0,0};
            *(short8*)&As[base] = z; *(short8*)&As[base + 8] = z;
            *(short8*)&Xs[base] = z; *(short8*)&Xs[base + 8] = z;
        }
    }
    __syncthreads();

    const int c0 = w * 64;
    const int lc = lane & 15;
    const int lg = lane >> 4;
    const int kg = lg * 8;

    float4v accg[2][4], accs[2][4];
    #pragma unroll
    for (int ct = 0; ct < 4; ++ct) {
        int col = c0 + ct * 16 + lc;
        float bgv = bg[col], bsv = bs[col];
        float4v vg = {bgv, bgv, bgv, bgv};
        float4v vs = {bsv, bsv, bsv, bsv};
        accg[0][ct] = vg; accg[1][ct] = vg;
        accs[0][ct] = vs; accs[1][ct] = vs;
    }

    #pragma unroll
    for (int ks = 0; ks < 4; ++ks) {
        short8 afa[2], afx[2];
        #pragma unroll
        for (int rt = 0; rt < 2; ++rt) {
            int off = (rt * 16 + lc) * 136 + ks * 32 + kg;
            afa[rt] = *(const short8*)&As[off];
            afx[rt] = *(const short8*)&Xs[off];
        }
        #pragma unroll
        for (int ct = 0; ct < 4; ++ct) {
            int col = c0 + ct * 16 + lc;
            size_t woff = (size_t)col * DIM_IN + ks * 32 + kg;
            short8 bfg = *(const short8*)(wtg + woff);
            short8 bfs = *(const short8*)(wts + woff);
            #pragma unroll
            for (int rt = 0; rt < 2; ++rt) {
                accg[rt][ct] = __builtin_amdgcn_mfma_f32_16x16x32_bf16(afa[rt], bfg, accg[rt][ct], 0, 0, 0);
                accs[rt][ct] = __builtin_amdgcn_mfma_f32_16x16x32_bf16(afx[rt], bfs, accs[rt][ct], 0, 0, 0);
            }
        }
    }

    #pragma unroll
    for (int rt = 0; rt < 2; ++rt) {
        #pragma unroll
        for (int r = 0; r < 4; ++r) {
            int row = r0 + rt * 16 + lg * 4 + r;
            if (row < N_NODES) {
                #pragma unroll
                for (int ct = 0; ct < 4; ++ct) {
                    int col = c0 + ct * 16 + lc;
                    ogb[(size_t)row * DIM_OUT + col] = f2bf(accg[rt][ct][r]);
                    out[(size_t)row * DIM_OUT + col] = accs[rt][ct][r];
                }
            }
        }
    }
}

__global__ __launch_bounds__(256) void k_colstats(const unsigned short* __restrict__ ogb,
                                                  float* __restrict__ sums,
                                                  float* __restrict__ sumsq) {
    const int c = threadIdx.x;
    float s = 0.f, q = 0.f;
    for (int r = blockIdx.x; r < N_NODES; r += gridDim.x) {
        float v = bf2f(ogb[(size_t)r * DIM_OUT + c]);
        s += v;
        q += v * v;
    }
    atomicAdd(&sums[c], s);
    atomicAdd(&sumsq[c], q);
}

__global__ void k_bnparams(const float* __restrict__ sums, const float* __restrict__ sumsq,
                           const float* __restrict__ gamma, const float* __restrict__ beta,
                           float* __restrict__ scale, float* __restrict__ shift) {
    const int c = threadIdx.x;
    const float inv_n = 1.f / (float)N_NODES;
    float mean = sums[c] * inv_n;
    float var  = fmaxf(sumsq[c] * inv_n - mean * mean, 0.f);
    float sc   = gamma[c] * rsqrtf(var + EPS_BN);
    scale[c] = sc;
    shift[c] = beta[c] - mean * sc;
}

// out += elu(og*scale + shift)   (out already holds sc = x@Ws + bs, f32)
__global__ __launch_bounds__(256) void k_final(const unsigned short* __restrict__ ogb,
                                               const float* __restrict__ scale,
                                               const float* __restrict__ shift,
                                               float* __restrict__ out) {
    size_t i4 = (size_t)blockIdx.x * blockDim.x + threadIdx.x;
    size_t base = i4 * 4;
    int c0 = (int)(base & (DIM_OUT - 1));
    ushort4 v = *(const ushort4*)(ogb + base);
    float4 s = *(const float4*)(out + base);

    float vv[4] = {bf2f(v.x), bf2f(v.y), bf2f(v.z), bf2f(v.w)};
    float sv[4] = {s.x, s.y, s.z, s.w};
    float4 o;
    float* op = &o.x;
    #pragma unroll
    for (int j = 0; j < 4; ++j) {
        float b = vv[j] * scale[c0 + j] + shift[c0 + j];
        float e = (b > 0.f) ? b : expm1f(b);
        op[j] = sv[j] + e;
    }
    *(float4*)(out + base) = o;
}

extern "C" void kernel_launch(void* const* d_in, const int* in_sizes, int n_in,
                              void* d_out, int out_size, void* d_ws, size_t ws_size,
                              hipStream_t stream) {
    const float* x     = (const float*)d_in[0];
    const void*  edges = d_in[1];
    const float* Wg    = (const float*)d_in[2];
    const float* bg    = (const float*)d_in[3];
    const float* gamma = (const float*)d_in[4];
    const float* beta  = (const float*)d_in[5];
    const float* Wsc   = (const float*)d_in[6];
    const float* bsc   = (const float*)d_in[7];

    float* ws    = (float*)d_ws;
    unsigned short* xb   = (unsigned short*)(ws + OFF_XB);
    unsigned short* aggb = (unsigned short*)(ws + OFF_AGGB);
    unsigned short* ogb  = (unsigned short*)(ws + OFF_OG);
    float* sums  = ws + OFF_STATS;
    float* sumsq = sums + 256;
    float* scale = sums + 512;
    float* shift = sums + 768;
    int*   flag  = (int*)(sums + 1024);
    unsigned short* wtg = (unsigned short*)(sums + 1040);  // 256*128 bf16
    unsigned short* wts = wtg + 256 * 128;
    float* out   = (float*)d_out;

    // CSR scratch overlaid at start of og region (dead before k_gemm_mfma writes ogb)
    int* ib     = (int*)(ws + OFF_OG);
    int* deg    = ib;
    int* offs   = ib + 50000;    // 50001
    int* cursor = ib + 100001;   // 50000
    int* bsum   = ib + 150001;   // 256
    int* boff   = ib + 150257;   // 256
    int* srcs   = ib + 150513;   // 600000

    hipMemsetAsync(deg, 0, N_NODES * sizeof(int), stream);
    hipMemsetAsync(sums, 0, 512 * sizeof(float), stream);

    k_detect<<<1, 256, 0, stream>>>((const unsigned int*)edges, flag);
    k_hist<<<(N_EDGES + 255) / 256, 256, 0, stream>>>(edges, deg, flag);
    k_scan_a<<<NBLK_SCAN, 256, 0, stream>>>(deg, bsum);
    k_scan_b<<<1, 256, 0, stream>>>(bsum, boff);
    k_scan_c<<<NBLK_SCAN, 256, 0, stream>>>(deg, boff, offs, cursor);
    k_fill<<<(N_EDGES + 255) / 256, 256, 0, stream>>>(edges, cursor, srcs, flag);
    k_cvt<<<NBLK_CVTX + 1, 256, 0, stream>>>(x, Wg, Wsc, xb, wtg, wts);
    k_gather<<<(N_NODES * 64) / 256, 256, 0, stream>>>(xb, offs, srcs, aggb);
    k_gemm_mfma<<<(N_NODES + 31) / 32, 256, 0, stream>>>(aggb, xb, wtg, wts, bg, bsc, ogb, out);
    k_colstats<<<256, 256, 0, stream>>>(ogb, sums, sumsq);
    k_bnparams<<<1, 256, 0, stream>>>(sums, sumsq, gamma, beta, scale, shift);
    k_final<<<(N_NODES * DIM_OUT / 4) / 256, 256, 0, stream>>>(ogb, scale, shift, out);
}

// Round 11
// 220.531 us; speedup vs baseline: 6.0081x; 1.1537x over previous
//
#include <hip/hip_runtime.h>
#include <hip/hip_bf16.h>

#define N_NODES 50000
#define N_EDGES 600000
#define DIM_IN  128
#define DIM_OUT 256
#define EPS_BN  1e-5f
#define NBLK_SCAN 196   // ceil(50000/256)
#define NBLK_CVTX 3125  // 50000*128/8/256
#define NBLK_CS   512   // colstats blocks

// ---- ws layout (float offsets) ----
// xb    : [0, 3.2M)        x as bf16 (6.4M ushort)
// aggb  : [3.2M, 6.4M)     agg as bf16 (6.4M ushort)
// ogb   : [6.4M, 12.8M)    og as bf16 (12.8M ushort); CSR int scratch overlaid at start
// stats : base 19.2M: sums[256], sumsq[256], scale[256], shift[256], flag, pad, Wt bf16
#define OFF_XB    0
#define OFF_AGGB  3200000
#define OFF_OG    6400000
#define OFF_STATS 19200000

typedef __attribute__((ext_vector_type(8))) short short8;
typedef __attribute__((ext_vector_type(8))) unsigned short ushort8;
typedef __attribute__((ext_vector_type(4))) float float4v;

__device__ __forceinline__ unsigned short f2bf(float f) {
    unsigned int x = __builtin_bit_cast(unsigned int, f);
    unsigned int r = (x + 0x7fffu + ((x >> 16) & 1u)) >> 16;   // RNE
    return (unsigned short)r;
}
__device__ __forceinline__ float bf2f(unsigned short b) {
    unsigned int u = ((unsigned int)b) << 16;
    return __builtin_bit_cast(float, u);
}

// Detect whether edges buffer is int64 (flag=1) or int32 (flag=0).
__global__ void k_detect(const unsigned int* __restrict__ e, int* __restrict__ flag) {
    __shared__ int nz;
    if (threadIdx.x == 0) nz = 0;
    __syncthreads();
    int c = 0;
    for (int i = threadIdx.x; i < 1024; i += 256) c += (e[2 * i + 1] != 0u);
    if (c) atomicAdd(&nz, c);
    __syncthreads();
    if (threadIdx.x == 0) *flag = (nz == 0) ? 1 : 0;
}

__device__ __forceinline__ int load_edge(const void* edges, int idx, int flag) {
    return flag ? (int)((const long long*)edges)[idx] : ((const int*)edges)[idx];
}

__global__ __launch_bounds__(256) void k_hist(const void* __restrict__ edges,
                                              int* __restrict__ deg,
                                              const int* __restrict__ flag) {
    int e = blockIdx.x * 256 + threadIdx.x;
    if (e >= N_EDGES) return;
    int d = load_edge(edges, N_EDGES + e, *flag);
    atomicAdd(&deg[d], 1);
}

__global__ __launch_bounds__(256) void k_scan_a(const int* __restrict__ deg, int* __restrict__ bsum) {
    __shared__ int sm[256];
    int t = threadIdx.x;
    int i = blockIdx.x * 256 + t;
    sm[t] = (i < N_NODES) ? deg[i] : 0;
    __syncthreads();
    for (int s = 128; s > 0; s >>= 1) {
        if (t < s) sm[t] += sm[t + s];
        __syncthreads();
    }
    if (t == 0) bsum[blockIdx.x] = sm[0];
}

__global__ void k_scan_b(const int* __restrict__ bsum, int* __restrict__ boff) {
    __shared__ int sm[256];
    int t = threadIdx.x;
    int v = (t < NBLK_SCAN) ? bsum[t] : 0;
    sm[t] = v;
    __syncthreads();
    for (int o = 1; o < 256; o <<= 1) {
        int u = (t >= o) ? sm[t - o] : 0;
        __syncthreads();
        sm[t] += u;
        __syncthreads();
    }
    boff[t] = sm[t] - v;   // exclusive
}

__global__ __launch_bounds__(256) void k_scan_c(const int* __restrict__ deg,
                                                const int* __restrict__ boff,
                                                int* __restrict__ offs,
                                                int* __restrict__ cursor) {
    __shared__ int sm[256];
    int t = threadIdx.x;
    int i = blockIdx.x * 256 + t;
    int v = (i < N_NODES) ? deg[i] : 0;
    sm[t] = v;
    __syncthreads();
    for (int o = 1; o < 256; o <<= 1) {
        int u = (t >= o) ? sm[t - o] : 0;
        __syncthreads();
        sm[t] += u;
        __syncthreads();
    }
    if (i < N_NODES) {
        int ex = boff[blockIdx.x] + sm[t] - v;
        offs[i] = ex;
        cursor[i] = ex;
    }
    if (i == 0) offs[N_NODES] = N_EDGES;
}

__global__ __launch_bounds__(256) void k_fill(const void* __restrict__ edges,
                                              int* __restrict__ cursor,
                                              int* __restrict__ srcs,
                                              const int* __restrict__ flag) {
    int e = blockIdx.x * 256 + threadIdx.x;
    if (e >= N_EDGES) return;
    int f = *flag;
    int s = load_edge(edges, e, f);
    int d = load_edge(edges, N_EDGES + e, f);
    int slot = atomicAdd(&cursor[d], 1);
    srcs[slot] = s;
}

// Merged conversions: blocks [0, NBLK_CVTX) convert x -> xb (bf16);
// block NBLK_CVTX transposes+converts both weight matrices.
__global__ __launch_bounds__(256) void k_cvt(const float* __restrict__ x,
                                             const float* __restrict__ Wg,
                                             const float* __restrict__ Ws,
                                             unsigned short* __restrict__ xb,
                                             unsigned short* __restrict__ wtg,
                                             unsigned short* __restrict__ wts) {
    int bid = blockIdx.x;
    if (bid < NBLK_CVTX) {
        size_t i = ((size_t)bid * 256 + threadIdx.x) * 8;
        float4 a = *(const float4*)(x + i);
        float4 b = *(const float4*)(x + i + 4);
        short8 s;
        s[0]=(short)f2bf(a.x); s[1]=(short)f2bf(a.y); s[2]=(short)f2bf(a.z); s[3]=(short)f2bf(a.w);
        s[4]=(short)f2bf(b.x); s[5]=(short)f2bf(b.y); s[6]=(short)f2bf(b.z); s[7]=(short)f2bf(b.w);
        *(short8*)(xb + i) = s;
    } else {
        int n = threadIdx.x;
        for (int k = 0; k < DIM_IN; ++k) {
            wtg[n * DIM_IN + k] = f2bf(Wg[k * DIM_OUT + n]);
            wts[n * DIM_IN + k] = f2bf(Ws[k * DIM_OUT + n]);
        }
    }
}

// One 64-lane wave per dst row; lane covers 2 cols. Src indices are loaded 64-at-a-time
// coalesced, shfl-broadcast; row loads issued in unrolled groups of 4 (independent -> MLP).
__global__ __launch_bounds__(256) void k_gather(const unsigned short* __restrict__ xb,
                                                const int* __restrict__ offs,
                                                const int* __restrict__ srcs,
                                                unsigned short* __restrict__ aggb) {
    int gid = blockIdx.x * 256 + threadIdx.x;
    int row = gid >> 6;
    int lane = threadIdx.x & 63;
    int b = offs[row], e = offs[row + 1];
    float ax = 0.f, ay = 0.f;
    for (int i0 = b; i0 < e; i0 += 64) {
        int cnt = min(64, e - i0);
        int si = (i0 + lane < e) ? srcs[i0 + lane] : 0;
        int j = 0;
        for (; j + 4 <= cnt; j += 4) {
            float tx[4], ty[4];
            #pragma unroll
            for (int u4 = 0; u4 < 4; ++u4) {
                int s = __shfl(si, j + u4, 64);
                unsigned int u = *(const unsigned int*)(xb + (size_t)s * DIM_IN + lane * 2);
                tx[u4] = __builtin_bit_cast(float, u << 16);
                ty[u4] = __builtin_bit_cast(float, u & 0xffff0000u);
            }
            ax += (tx[0] + tx[1]) + (tx[2] + tx[3]);
            ay += (ty[0] + ty[1]) + (ty[2] + ty[3]);
        }
        for (; j < cnt; ++j) {
            int s = __shfl(si, j, 64);
            unsigned int u = *(const unsigned int*)(xb + (size_t)s * DIM_IN + lane * 2);
            ax += __builtin_bit_cast(float, u << 16);
            ay += __builtin_bit_cast(float, u & 0xffff0000u);
        }
    }
    unsigned int o = ((unsigned int)f2bf(ax)) | (((unsigned int)f2bf(ay)) << 16);
    *(unsigned int*)(aggb + (size_t)row * DIM_IN + lane * 2) = o;
}

// Dual MFMA GEMM: og(bf16) = agg@Wg + bg, sc(f32->d_out) = x@Ws + bs.
__global__ __launch_bounds__(256) void k_gemm_mfma(const unsigned short* __restrict__ aggb,
                                                   const unsigned short* __restrict__ xb,
                                                   const unsigned short* __restrict__ wtg,
                                                   const unsigned short* __restrict__ wts,
                                                   const float* __restrict__ bg,
                                                   const float* __restrict__ bs,
                                                   unsigned short* __restrict__ ogb,
                                                   float* __restrict__ out) {
    __shared__ short As[32 * 136];
    __shared__ short Xs[32 * 136];
    const int r0 = blockIdx.x * 32;
    const int t = threadIdx.x;
    const int lane = t & 63;
    const int w = t >> 6;

    {
        int row = t >> 3;
        int cs  = (t & 7) * 16;
        int grow = r0 + row;
        int base = row * 136 + cs;
        if (grow < N_NODES) {
            const short8* pa = (const short8*)(aggb + (size_t)grow * DIM_IN + cs);
            const short8* px = (const short8*)(xb   + (size_t)grow * DIM_IN + cs);
            *(short8*)&As[base]     = pa[0];
            *(short8*)&As[base + 8] = pa[1];
            *(short8*)&Xs[base]     = px[0];
            *(short8*)&Xs[base + 8] = px[1];
        } else {
            short8 z = {0,0,0,0,0,0,0,0};
            *(short8*)&As[base] = z; *(short8*)&As[base + 8] = z;
            *(short8*)&Xs[base] = z; *(short8*)&Xs[base + 8] = z;
        }
    }
    __syncthreads();

    const int c0 = w * 64;
    const int lc = lane & 15;
    const int lg = lane >> 4;
    const int kg = lg * 8;

    float4v accg[2][4], accs[2][4];
    #pragma unroll
    for (int ct = 0; ct < 4; ++ct) {
        int col = c0 + ct * 16 + lc;
        float bgv = bg[col], bsv = bs[col];
        float4v vg = {bgv, bgv, bgv, bgv};
        float4v vs = {bsv, bsv, bsv, bsv};
        accg[0][ct] = vg; accg[1][ct] = vg;
        accs[0][ct] = vs; accs[1][ct] = vs;
    }

    #pragma unroll
    for (int ks = 0; ks < 4; ++ks) {
        short8 afa[2], afx[2];
        #pragma unroll
        for (int rt = 0; rt < 2; ++rt) {
            int off = (rt * 16 + lc) * 136 + ks * 32 + kg;
            afa[rt] = *(const short8*)&As[off];
            afx[rt] = *(const short8*)&Xs[off];
        }
        #pragma unroll
        for (int ct = 0; ct < 4; ++ct) {
            int col = c0 + ct * 16 + lc;
            size_t woff = (size_t)col * DIM_IN + ks * 32 + kg;
            short8 bfg = *(const short8*)(wtg + woff);
            short8 bfs = *(const short8*)(wts + woff);
            #pragma unroll
            for (int rt = 0; rt < 2; ++rt) {
                accg[rt][ct] = __builtin_amdgcn_mfma_f32_16x16x32_bf16(afa[rt], bfg, accg[rt][ct], 0, 0, 0);
                accs[rt][ct] = __builtin_amdgcn_mfma_f32_16x16x32_bf16(afx[rt], bfs, accs[rt][ct], 0, 0, 0);
            }
        }
    }

    #pragma unroll
    for (int rt = 0; rt < 2; ++rt) {
        #pragma unroll
        for (int r = 0; r < 4; ++r) {
            int row = r0 + rt * 16 + lg * 4 + r;
            if (row < N_NODES) {
                #pragma unroll
                for (int ct = 0; ct < 4; ++ct) {
                    int col = c0 + ct * 16 + lc;
                    ogb[(size_t)row * DIM_OUT + col] = f2bf(accg[rt][ct][r]);
                    out[(size_t)row * DIM_OUT + col] = accs[rt][ct][r];
                }
            }
        }
    }
}

// Vectorized column stats: thread owns 8 consecutive cols (ushort8 = 16B loads),
// wave covers 2 rows x 512B contiguous. Grid-stride over rows, LDS reduce, atomics.
__global__ __launch_bounds__(256) void k_colstats(const unsigned short* __restrict__ ogb,
                                                  float* __restrict__ sums,
                                                  float* __restrict__ sumsq) {
    __shared__ float lds_s[8][256];
    __shared__ float lds_q[8][256];
    const int t  = threadIdx.x;
    const int rg = t >> 5;             // row-group 0..7
    const int cg = (t & 31) * 8;       // first of 8 columns
    float s[8] = {0,0,0,0,0,0,0,0}, q[8] = {0,0,0,0,0,0,0,0};
    for (int r = blockIdx.x * 8 + rg; r < N_NODES; r += NBLK_CS * 8) {
        ushort8 v = *(const ushort8*)(ogb + (size_t)r * DIM_OUT + cg);
        #pragma unroll
        for (int j = 0; j < 8; ++j) {
            float f = bf2f(v[j]);
            s[j] += f;
            q[j] += f * f;
        }
    }
    #pragma unroll
    for (int j = 0; j < 8; ++j) {
        lds_s[rg][cg + j] = s[j];
        lds_q[rg][cg + j] = q[j];
    }
    __syncthreads();
    // thread t reduces column t across the 8 row-groups
    float S = 0.f, Q = 0.f;
    #pragma unroll
    for (int g = 0; g < 8; ++g) {
        S += lds_s[g][t];
        Q += lds_q[g][t];
    }
    atomicAdd(&sums[t], S);
    atomicAdd(&sumsq[t], Q);
}

__global__ void k_bnparams(const float* __restrict__ sums, const float* __restrict__ sumsq,
                           const float* __restrict__ gamma, const float* __restrict__ beta,
                           float* __restrict__ scale, float* __restrict__ shift) {
    const int c = threadIdx.x;
    const float inv_n = 1.f / (float)N_NODES;
    float mean = sums[c] * inv_n;
    float var  = fmaxf(sumsq[c] * inv_n - mean * mean, 0.f);
    float sc   = gamma[c] * rsqrtf(var + EPS_BN);
    scale[c] = sc;
    shift[c] = beta[c] - mean * sc;
}

// out += elu(og*scale + shift)   (out already holds sc = x@Ws + bs, f32)
__global__ __launch_bounds__(256) void k_final(const unsigned short* __restrict__ ogb,
                                               const float* __restrict__ scale,
                                               const float* __restrict__ shift,
                                               float* __restrict__ out) {
    size_t i4 = (size_t)blockIdx.x * blockDim.x + threadIdx.x;
    size_t base = i4 * 4;
    int c0 = (int)(base & (DIM_OUT - 1));
    ushort4 v = *(const ushort4*)(ogb + base);
    float4 s = *(const float4*)(out + base);

    float vv[4] = {bf2f(v.x), bf2f(v.y), bf2f(v.z), bf2f(v.w)};
    float sv[4] = {s.x, s.y, s.z, s.w};
    float4 o;
    float* op = &o.x;
    #pragma unroll
    for (int j = 0; j < 4; ++j) {
        float b = vv[j] * scale[c0 + j] + shift[c0 + j];
        float e = (b > 0.f) ? b : expm1f(b);
        op[j] = sv[j] + e;
    }
    *(float4*)(out + base) = o;
}

extern "C" void kernel_launch(void* const* d_in, const int* in_sizes, int n_in,
                              void* d_out, int out_size, void* d_ws, size_t ws_size,
                              hipStream_t stream) {
    const float* x     = (const float*)d_in[0];
    const void*  edges = d_in[1];
    const float* Wg    = (const float*)d_in[2];
    const float* bg    = (const float*)d_in[3];
    const float* gamma = (const float*)d_in[4];
    const float* beta  = (const float*)d_in[5];
    const float* Wsc   = (const float*)d_in[6];
    const float* bsc   = (const float*)d_in[7];

    float* ws    = (float*)d_ws;
    unsigned short* xb   = (unsigned short*)(ws + OFF_XB);
    unsigned short* aggb = (unsigned short*)(ws + OFF_AGGB);
    unsigned short* ogb  = (unsigned short*)(ws + OFF_OG);
    float* sums  = ws + OFF_STATS;
    float* sumsq = sums + 256;
    float* scale = sums + 512;
    float* shift = sums + 768;
    int*   flag  = (int*)(sums + 1024);
    unsigned short* wtg = (unsigned short*)(sums + 1040);  // 256*128 bf16
    unsigned short* wts = wtg + 256 * 128;
    float* out   = (float*)d_out;

    // CSR scratch overlaid at start of og region (dead before k_gemm_mfma writes ogb)
    int* ib     = (int*)(ws + OFF_OG);
    int* deg    = ib;
    int* offs   = ib + 50000;    // 50001
    int* cursor = ib + 100001;   // 50000
    int* bsum   = ib + 150001;   // 256
    int* boff   = ib + 150257;   // 256
    int* srcs   = ib + 150513;   // 600000

    hipMemsetAsync(deg, 0, N_NODES * sizeof(int), stream);
    hipMemsetAsync(sums, 0, 512 * sizeof(float), stream);

    k_detect<<<1, 256, 0, stream>>>((const unsigned int*)edges, flag);
    k_hist<<<(N_EDGES + 255) / 256, 256, 0, stream>>>(edges, deg, flag);
    k_scan_a<<<NBLK_SCAN, 256, 0, stream>>>(deg, bsum);
    k_scan_b<<<1, 256, 0, stream>>>(bsum, boff);
    k_scan_c<<<NBLK_SCAN, 256, 0, stream>>>(deg, boff, offs, cursor);
    k_fill<<<(N_EDGES + 255) / 256, 256, 0, stream>>>(edges, cursor, srcs, flag);
    k_cvt<<<NBLK_CVTX + 1, 256, 0, stream>>>(x, Wg, Wsc, xb, wtg, wts);
    k_gather<<<(N_NODES * 64) / 256, 256, 0, stream>>>(xb, offs, srcs, aggb);
    k_gemm_mfma<<<(N_NODES + 31) / 32, 256, 0, stream>>>(aggb, xb, wtg, wts, bg, bsc, ogb, out);
    k_colstats<<<NBLK_CS, 256, 0, stream>>>(ogb, sums, sumsq);
    k_bnparams<<<1, 256, 0, stream>>>(sums, sumsq, gamma, beta, scale, shift);
    k_final<<<(N_NODES * DIM_OUT / 4) / 256, 256, 0, stream>>>(ogb, scale, shift, out);
}